// Round 5
// baseline (98.186 us; speedup 1.0000x reference)
//
#include <hip/hip_runtime.h>
#include <hip/hip_bf16.h>
#include <stdint.h>

typedef unsigned int uint32;
typedef unsigned short u16;
typedef __attribute__((ext_vector_type(8))) short bf16x8;
typedef __attribute__((ext_vector_type(4))) float f32x4;

// ws float-offsets
#define WS_SCALE 0
#define WS_SHIFT 512
#define WS_SUBQ  1024            // 6*512 f32 (sub[0]=0)
#define WS_SUBQB 4096            // 6*512 bf16 (as 1536 floats)
#define WS_PSUM  8192            // 256*512
#define WS_PSQ   (8192+131072)
// ws byte offsets
#define WRT_OFF  (2u<<20)        // 128 chunks * 8192 u16 = 2 MB
#define AMIN_OFF (4u<<20)        // 8192*1024 bf16 = 16 MB (plain row-major)
#define PART_OFF (21u<<20)       // 8*8192*256 bf16 = 32 MB
#define NRM_OFF  (54u<<20)       // 8192*512 bf16 = 8 MB

__device__ __forceinline__ u16 f2bf(float f){
  uint32 u; __builtin_memcpy(&u,&f,4);
  u = u + 0x7fffu + ((u>>16)&1u);
  return (u16)(u>>16);
}
__device__ __forceinline__ float bf2f(u16 b){
  uint32 u = ((uint32)b)<<16; float f; __builtin_memcpy(&f,&u,4); return f;
}
__device__ __forceinline__ uint32 pk2(float a, float b){
  return (uint32)f2bf(a) | ((uint32)f2bf(b)<<16);
}
__device__ __forceinline__ float plo(uint32 p){ uint32 u=p<<16; float f; __builtin_memcpy(&f,&u,4); return f; }
__device__ __forceinline__ float phi(uint32 p){ uint32 u=p&0xffff0000u; float f; __builtin_memcpy(&f,&u,4); return f; }
__device__ __forceinline__ void gll16(u16* lds, const u16* g){
  __builtin_amdgcn_global_load_lds((const __attribute__((address_space(1))) uint32*)g,
                                   (__attribute__((address_space(3))) uint32*)lds, 16, 0, 0);
}

// ---------------- fused: stats partials (blocks 0..255, 32 rows each) + w reorder (blocks 256..383) ----------------
__global__ __launch_bounds__(512) void k_pre(const float* __restrict__ x,
                                             const float* __restrict__ w,
                                             float* __restrict__ ws,
                                             u16* __restrict__ wrT){
  int b = blockIdx.x, t = threadIdx.x;
  if (b < 256){
    const float* xp = x + (size_t)b*32*512 + t;
    float sum = 0.f, sq = 0.f;
    #pragma unroll 8
    for (int r=0; r<32; ++r){ float v = xp[(size_t)r*512]; sum += v; sq += v*v; }
    ws[WS_PSUM + b*512 + t] = sum;
    ws[WS_PSQ  + b*512 + t] = sq;
  } else {
    int c2 = b - 256;            // 0..127 K-chunks of 32
    int o = t & 255, half = t >> 8;
    int swzrow = (o >> 1) & 3;
    u16* dst = wrT + (size_t)c2*8192 + o*32;
    #pragma unroll
    for (int gi=0; gi<2; ++gi){
      int g = half*2 + gi;
      union { bf16x8 v; u16 h[8]; } R;
      #pragma unroll
      for (int e=0; e<8; ++e){
        int k = g*8 + e;
        int sk;
        if (c2 < 96) sk = ((c2 & 15)*32 + k)*6 + (c2 >> 4);
        else         sk = 3072 + (c2 - 96)*32 + k;
        R.h[e] = f2bf(w[(size_t)sk*256 + o]);
      }
      *(bf16x8*)(dst + ((g ^ swzrow)*8)) = R.v;
    }
  }
}

// ---------------- stats finalize: 16 blocks x 32 cols ----------------
__global__ __launch_bounds__(512) void k_stats_final(const float* __restrict__ beta,
                                                     const float* __restrict__ gamma,
                                                     float* __restrict__ ws){
  __shared__ float rs[16][32], rq[16][32];
  int t = threadIdx.x;
  int nl = t & 31, sl = t >> 5;
  int n = blockIdx.x*32 + nl;
  float sum=0.f, sq=0.f;
  #pragma unroll
  for (int j=0;j<16;++j){
    int p = sl*16 + j;
    sum += ws[WS_PSUM + p*512 + n];
    sq  += ws[WS_PSQ  + p*512 + n];
  }
  rs[sl][nl]=sum; rq[sl][nl]=sq;
  __syncthreads();
  if (sl==0){
    #pragma unroll
    for (int j=1;j<16;++j){ sum+=rs[j][nl]; sq+=rq[j][nl]; }
    float mean = sum * (1.0f/8192.0f);
    float var  = sq  * (1.0f/8192.0f) - mean*mean;
    float g = gamma[n], b = beta[n];
    float inv = 1.0f / sqrtf(var + 0.001f);
    float scale = g * inv;
    float shift = b - mean*scale;
    ws[WS_SCALE + n] = scale;
    ws[WS_SHIFT + n] = shift;
    u16* subqb = (u16*)(ws + WS_SUBQB);
    const float QC[5] = {-3.0f, -0.834f, -0.248f, 0.248f, 0.834f};
    ws[WS_SUBQ + n] = 0.f;
    subqb[n] = 0;
    #pragma unroll
    for (int c=0; c<5; ++c){
      float sub = (QC[c]*var + mean)*g - b;
      ws[WS_SUBQ + (c+1)*512 + n] = sub;
      subqb[(c+1)*512 + n] = f2bf(sub);
    }
  }
}

// ---------------- min-feature A'' (plain row-major) + normed bf16 matrix ----------------
__global__ __launch_bounds__(256) void k_minfeat(const float* __restrict__ x,
                                                 const float* __restrict__ ws,
                                                 const int* __restrict__ ci,
                                                 u16* __restrict__ amin,
                                                 u16* __restrict__ nrmg){
  __shared__ float nrm[8][512];     // 16 KB
  __shared__ uint32 tnn[1024];
  __shared__ float ts1[1024];
  __shared__ float ts2[1024];
  int t = threadIdx.x;
  int b0 = blockIdx.x * 8;
  #pragma unroll
  for (int ii=0; ii<4; ++ii){
    int i = ii*256 + t;
    int n1 = ci[i*5+1], q1 = ci[i*5+2], n2 = ci[i*5+3], q2 = ci[i*5+4];
    tnn[i] = (uint32)n1 | ((uint32)n2 << 16);
    ts1[i] = ws[WS_SUBQ + q1*512 + n1];
    ts2[i] = ws[WS_SUBQ + q2*512 + n2];
  }
  {
    int r = t >> 5, c0 = (t & 31) * 16;
    const float* xr = x + (size_t)(b0 + r)*512 + c0;
    u16* ng = nrmg + (size_t)(b0 + r)*512 + c0;
    #pragma unroll
    for (int j=0;j<4;++j){
      float4 v  = *(const float4*)(xr + j*4);
      float4 sc = *(const float4*)(ws + WS_SCALE + c0 + j*4);
      float4 sh = *(const float4*)(ws + WS_SHIFT + c0 + j*4);
      float4 o; o.x=fmaf(v.x,sc.x,sh.x); o.y=fmaf(v.y,sc.y,sh.y);
      o.z=fmaf(v.z,sc.z,sh.z); o.w=fmaf(v.w,sc.w,sh.w);
      *(float4*)(&nrm[r][c0+j*4]) = o;
      uint2 pv; pv.x = pk2(o.x,o.y); pv.y = pk2(o.z,o.w);
      *(uint2*)(ng + j*4) = pv;
    }
  }
  __syncthreads();
  int m0 = t*4;
  uint4  nn = *(const uint4*)(&tnn[m0]);
  float4 s1 = *(const float4*)(&ts1[m0]);
  float4 s2 = *(const float4*)(&ts2[m0]);
  #pragma unroll
  for (int r=0;r<8;++r){
    float v0 = fminf(fmaxf(nrm[r][nn.x & 0xffff] - s1.x, 0.f), fmaxf(nrm[r][nn.x >> 16] - s2.x, 0.f));
    float v1 = fminf(fmaxf(nrm[r][nn.y & 0xffff] - s1.y, 0.f), fmaxf(nrm[r][nn.y >> 16] - s2.y, 0.f));
    float v2 = fminf(fmaxf(nrm[r][nn.z & 0xffff] - s1.z, 0.f), fmaxf(nrm[r][nn.z >> 16] - s2.z, 0.f));
    float v3 = fminf(fmaxf(nrm[r][nn.w & 0xffff] - s1.w, 0.f), fmaxf(nrm[r][nn.w >> 16] - s2.w, 0.f));
    uint2 pv; pv.x = pk2(v0,v1); pv.y = pk2(v2,v3);
    *(uint2*)(amin + (size_t)(b0 + r)*1024 + m0) = pv;
  }
}

// ---------------- split-K=8 feature-GEMM, A built in registers ----------------
// 512 blocks: d = s*64 + mtile (XCD = mtile%8 -> splits of a mtile co-XCD).
// BM=128, BN=256, BK=32, 16 chunks. 8 waves (2Mx4N), wave tile 64x64, acc[4][4] 16x16x32.
// Only W tile in LDS (2x16KB, gll-staged, issued at iter top). A: b128 global (nrm/amin) -> regs.
__global__ __launch_bounds__(512,4) void k_gemm(const u16* __restrict__ nrmg,
                                                const u16* __restrict__ ws16,   // subqb
                                                const u16* __restrict__ wrT,
                                                const u16* __restrict__ amin,
                                                u16* __restrict__ parts){
  __shared__ u16 wt[2][8192];      // 32 KB

  int t = threadIdx.x;
  int d = blockIdx.x;
  int mtile = d & 63, s = d >> 6;
  int brow = mtile * 128;
  bool isMin = (s >= 6);

  int lane = t & 63, wv = t >> 6;
  int wm = wv >> 2, wn = wv & 3;
  int lr = lane & 15, lk = lane >> 4;
  int wuni = t & ~63;
  const u16* wbase = wrT + (size_t)(s*16)*8192;

  const u16* arow; int astr;
  if (isMin){ arow = amin + (size_t)(brow + wm*64 + lr)*1024 + (s-6)*512; astr = 1024; }
  else      { arow = nrmg + (size_t)(brow + wm*64 + lr)*512;              astr = 512;  }
  const u16* subb = ws16 + s*512;

  int osw[4];
  #pragma unroll
  for (int ni=0; ni<4; ++ni){
    int o = wn*64 + ni*16 + lr;
    osw[ni] = o*32 + ((lk ^ ((o>>1)&3))*8);
  }
  f32x4 acc[4][4] = {};
  uint4 nv[4]; uint4 sb;

  auto wstage = [&](int cc){
    const u16* wsrc = wbase + (size_t)cc*8192;
    int nb = cc & 1;
    gll16(&wt[nb][wuni*8], wsrc + (size_t)t*8);
    gll16(&wt[nb][4096 + wuni*8], wsrc + 4096 + (size_t)t*8);
  };
  auto loadA = [&](int cc){
    int co = cc*32 + lk*8;
    #pragma unroll
    for (int mi=0; mi<4; ++mi)
      nv[mi] = *(const uint4*)(arow + (size_t)mi*16*astr + co);
    if (!isMin) sb = *(const uint4*)(subb + co);
  };
  auto compute = [&](int cb){
    union { bf16x8 v; uint4 q; } Af[4];
    if (isMin){
      #pragma unroll
      for (int mi=0; mi<4; ++mi) Af[mi].q = nv[mi];
    } else {
      #pragma unroll
      for (int mi=0; mi<4; ++mi){
        uint32 const* wq = (uint32 const*)&nv[mi];
        uint32 const* sq = (uint32 const*)&sb;
        union { bf16x8 v; uint32 u[4]; } R;
        #pragma unroll
        for (int j=0; j<4; ++j){
          float a0 = fmaxf(plo(wq[j]) - plo(sq[j]), 0.f);
          float a1 = fmaxf(phi(wq[j]) - phi(sq[j]), 0.f);
          __hip_bfloat162 h = __float22bfloat162_rn(float2{a0,a1});
          __builtin_memcpy(&R.u[j], &h, 4);
        }
        Af[mi].v = R.v;
      }
    }
    #pragma unroll
    for (int ni=0; ni<4; ++ni){
      bf16x8 Bf = *(const bf16x8*)(&wt[cb][osw[ni]]);
      #pragma unroll
      for (int mi=0; mi<4; ++mi)
        acc[mi][ni] = __builtin_amdgcn_mfma_f32_16x16x32_bf16(Af[mi].v, Bf, acc[mi][ni], 0, 0, 0);
    }
  };

  loadA(0);
  wstage(0);
  __syncthreads();
  for (int c=0; c<16; ++c){
    if (c < 15) wstage(c+1);
    compute(c & 1);
    if (c < 15) loadA(c+1);
    __syncthreads();
  }

  u16* pp = parts + ((size_t)s*8192 + brow)*256;
  #pragma unroll
  for (int mi=0; mi<4; ++mi)
    #pragma unroll
    for (int ni=0; ni<4; ++ni)
      #pragma unroll
      for (int r=0; r<4; ++r){
        int rl = wm*64 + mi*16 + lk*4 + r;
        int cl = wn*64 + ni*16 + lr;
        pp[(size_t)rl*256 + cl] = f2bf(acc[mi][ni][r]);
      }
}

// ---------------- reduce 8 bf16 partials + bias ----------------
__global__ __launch_bounds__(256) void k_reduce(const u16* __restrict__ parts,
                                                const float* __restrict__ biases,
                                                float* __restrict__ out){
  int i = (blockIdx.x*256 + threadIdx.x) * 8;
  float b = biases[0];
  float a[8];
  #pragma unroll
  for (int j=0;j<8;++j) a[j] = b;
  #pragma unroll
  for (int s2=0;s2<8;++s2){
    bf16x8 v = *(const bf16x8*)(parts + (size_t)s2*2097152 + i);
    #pragma unroll
    for (int j=0;j<8;++j) a[j] += bf2f((u16)v[j]);
  }
  float4 o0 = {a[0],a[1],a[2],a[3]}, o1 = {a[4],a[5],a[6],a[7]};
  *(float4*)(out + i) = o0;
  *(float4*)(out + i + 4) = o1;
}

extern "C" void kernel_launch(void* const* d_in, const int* in_sizes, int n_in,
                              void* d_out, int out_size, void* d_ws, size_t ws_size,
                              hipStream_t stream){
  const float* x      = (const float*)d_in[0];
  const float* beta   = (const float*)d_in[1];
  const float* gamma  = (const float*)d_in[2];
  const float* w      = (const float*)d_in[3];
  const float* biases = (const float*)d_in[4];
  const int*   ci     = (const int*)d_in[5];
  float* out = (float*)d_out;
  float* wsf = (float*)d_ws;
  u16* wrT   = (u16*)((char*)d_ws + WRT_OFF);
  u16* amin  = (u16*)((char*)d_ws + AMIN_OFF);
  u16* parts = (u16*)((char*)d_ws + PART_OFF);
  u16* nrmg  = (u16*)((char*)d_ws + NRM_OFF);
  const u16* subqb = (const u16*)(wsf + WS_SUBQB);

  k_pre         <<<384, 512, 0, stream>>>(x, w, wsf, wrT);
  k_stats_final <<<16,  512, 0, stream>>>(beta, gamma, wsf);
  k_minfeat     <<<1024,256, 0, stream>>>(x, wsf, ci, amin, nrmg);
  k_gemm        <<<512, 512, 0, stream>>>(nrmg, subqb, wrT, amin, parts);
  k_reduce      <<<1024,256, 0, stream>>>(parts, biases, out);
}

// Round 8
// 54.550 us; speedup vs baseline: 1.7999x; 1.7999x over previous
//
#include <hip/hip_runtime.h>
#include <stdint.h>

typedef unsigned int uint32;
typedef unsigned short u16;
typedef __attribute__((ext_vector_type(8))) short bf16x8;
typedef __attribute__((ext_vector_type(4))) float f32x4;

// ws float-offsets
#define WS_SCALE 0
#define WS_SHIFT 512
#define WS_SUBQ  1024            // 6*512 f32 (sub[0]=0)
#define WS_SHSUB 4096            // 6*512 f32 (shift - sub[q])
#define WS_PSUM  8192            // 256*512
#define WS_PSQ   (8192+131072)
// ws byte offsets
#define WRT_OFF  (2u<<20)        // 128 chunks * 8192 u16 = 2 MB
#define AMIN_OFF (4u<<20)        // 8192*1024 bf16 = 16 MB (rows pre-swizzled per 32-col chunk)
#define PART_OFF (21u<<20)       // 8*8192*256 bf16 = 32 MB

__device__ __forceinline__ u16 f2bf(float f){
  uint32 u; __builtin_memcpy(&u,&f,4);
  u = u + 0x7fffu + ((u>>16)&1u);
  return (u16)(u>>16);
}
__device__ __forceinline__ float bf2f(u16 b){
  uint32 u = ((uint32)b)<<16; float f; __builtin_memcpy(&f,&u,4); return f;
}
__device__ __forceinline__ uint32 pk2(float a, float b){
  return (uint32)f2bf(a) | ((uint32)f2bf(b)<<16);
}
__device__ __forceinline__ void gll16(u16* lds, const u16* g){
  __builtin_amdgcn_global_load_lds((const __attribute__((address_space(1))) uint32*)g,
                                   (__attribute__((address_space(3))) uint32*)lds, 16, 0, 0);
}

// ---------------- fused: stats partials (blocks 0..255, 32 rows each) + w reorder (blocks 256..383) ----------------
// wrT layout: 128 chunks of 32 k' (k' = q*512+n for k'<3072, then min rows).
// chunk c2: [o][32] u16, 16B-slot position = (g ^ ((o>>1)&3)), g = k>>3.
__global__ __launch_bounds__(512) void k_pre(const float* __restrict__ x,
                                             const float* __restrict__ w,
                                             float* __restrict__ ws,
                                             u16* __restrict__ wrT){
  int b = blockIdx.x, t = threadIdx.x;
  if (b < 256){
    const float* xp = x + (size_t)b*32*512 + t;
    float sum = 0.f, sq = 0.f;
    #pragma unroll 8
    for (int r=0; r<32; ++r){ float v = xp[(size_t)r*512]; sum += v; sq += v*v; }
    ws[WS_PSUM + b*512 + t] = sum;
    ws[WS_PSQ  + b*512 + t] = sq;
  } else {
    int c2 = b - 256;            // 0..127 K-chunks of 32
    int o = t & 255, half = t >> 8;
    int swzrow = (o >> 1) & 3;
    u16* dst = wrT + (size_t)c2*8192 + o*32;
    #pragma unroll
    for (int gi=0; gi<2; ++gi){
      int g = half*2 + gi;
      union { bf16x8 v; u16 h[8]; } R;
      #pragma unroll
      for (int e=0; e<8; ++e){
        int k = g*8 + e;
        int sk;
        if (c2 < 96) sk = ((c2 & 15)*32 + k)*6 + (c2 >> 4);
        else         sk = 3072 + (c2 - 96)*32 + k;
        R.h[e] = f2bf(w[(size_t)sk*256 + o]);
      }
      *(bf16x8*)(dst + ((g ^ swzrow)*8)) = R.v;
    }
  }
}

// ---------------- stats finalize: 16 blocks x 32 cols, tree reduce ----------------
__global__ __launch_bounds__(512) void k_stats_final(const float* __restrict__ beta,
                                                     const float* __restrict__ gamma,
                                                     float* __restrict__ ws){
  __shared__ float rs[16][32], rq[16][32];
  int t = threadIdx.x;
  int nl = t & 31, sl = t >> 5;
  int n = blockIdx.x*32 + nl;
  float sum=0.f, sq=0.f;
  #pragma unroll
  for (int j=0;j<16;++j){
    int p = sl*16 + j;
    sum += ws[WS_PSUM + p*512 + n];
    sq  += ws[WS_PSQ  + p*512 + n];
  }
  rs[sl][nl]=sum; rq[sl][nl]=sq;
  __syncthreads();
  if (sl==0){
    #pragma unroll
    for (int j=1;j<16;++j){ sum+=rs[j][nl]; sq+=rq[j][nl]; }
    float mean = sum * (1.0f/8192.0f);
    float var  = sq  * (1.0f/8192.0f) - mean*mean;
    float g = gamma[n], b = beta[n];
    float inv = 1.0f / sqrtf(var + 0.001f);
    float scale = g * inv;
    float shift = b - mean*scale;
    ws[WS_SCALE + n] = scale;
    ws[WS_SHIFT + n] = shift;
    const float QC[5] = {-3.0f, -0.834f, -0.248f, 0.248f, 0.834f};
    ws[WS_SUBQ  + n] = 0.f;
    ws[WS_SHSUB + n] = shift;
    #pragma unroll
    for (int c=0; c<5; ++c){
      float sub = (QC[c]*var + mean)*g - b;
      ws[WS_SUBQ  + (c+1)*512 + n] = sub;
      ws[WS_SHSUB + (c+1)*512 + n] = shift - sub;
    }
  }
}

// ---------------- min-feature matrix A'' (8192 x 1024 bf16, rows pre-swizzled per 32-col chunk) ----------------
__global__ __launch_bounds__(256) void k_minfeat(const float* __restrict__ x,
                                                 const float* __restrict__ ws,
                                                 const int* __restrict__ ci,
                                                 u16* __restrict__ amin){
  __shared__ float nrm[8][512];     // 16 KB
  __shared__ uint32 tnn[1024];
  __shared__ float ts1[1024];
  __shared__ float ts2[1024];
  int t = threadIdx.x;
  int b0 = blockIdx.x * 8;
  #pragma unroll
  for (int ii=0; ii<4; ++ii){
    int i = ii*256 + t;
    int n1 = ci[i*5+1], q1 = ci[i*5+2], n2 = ci[i*5+3], q2 = ci[i*5+4];
    tnn[i] = (uint32)n1 | ((uint32)n2 << 16);
    ts1[i] = ws[WS_SUBQ + q1*512 + n1];
    ts2[i] = ws[WS_SUBQ + q2*512 + n2];
  }
  {
    int r = t >> 5, c0 = (t & 31) * 16;
    const float* xr = x + (size_t)(b0 + r)*512 + c0;
    #pragma unroll
    for (int j=0;j<4;++j){
      float4 v  = *(const float4*)(xr + j*4);
      float4 sc = *(const float4*)(ws + WS_SCALE + c0 + j*4);
      float4 sh = *(const float4*)(ws + WS_SHIFT + c0 + j*4);
      float4 o; o.x=fmaf(v.x,sc.x,sh.x); o.y=fmaf(v.y,sc.y,sh.y);
      o.z=fmaf(v.z,sc.z,sh.z); o.w=fmaf(v.w,sc.w,sh.w);
      *(float4*)(&nrm[r][c0+j*4]) = o;
    }
  }
  __syncthreads();
  int m0 = t*4;
  uint4  nn = *(const uint4*)(&tnn[m0]);
  float4 s1 = *(const float4*)(&ts1[m0]);
  float4 s2 = *(const float4*)(&ts2[m0]);
  int cc = m0 >> 5, k = m0 & 31, g2 = k >> 3;
  #pragma unroll
  for (int r=0;r<8;++r){
    float v0 = fminf(fmaxf(nrm[r][nn.x & 0xffff] - s1.x, 0.f), fmaxf(nrm[r][nn.x >> 16] - s2.x, 0.f));
    float v1 = fminf(fmaxf(nrm[r][nn.y & 0xffff] - s1.y, 0.f), fmaxf(nrm[r][nn.y >> 16] - s2.y, 0.f));
    float v2 = fminf(fmaxf(nrm[r][nn.z & 0xffff] - s1.z, 0.f), fmaxf(nrm[r][nn.z >> 16] - s2.z, 0.f));
    float v3 = fminf(fmaxf(nrm[r][nn.w & 0xffff] - s1.w, 0.f), fmaxf(nrm[r][nn.w >> 16] - s2.w, 0.f));
    int pos = cc*32 + ((g2 ^ (((b0 + r) >> 1) & 3))*8) + (k & 7);
    uint2 pv; pv.x = pk2(v0,v1); pv.y = pk2(v2,v3);
    *(uint2*)(amin + (size_t)(b0 + r)*1024 + pos) = pv;
  }
}

// ---------------- split-K=8 fused feature-GEMM (r4 structure + x register prefetch) ----------------
// 512 blocks: d = s*64 + mtile (XCD = mtile%8 -> all splits of a mtile co-XCD).
// BM=128, BN=256, BK=32, 16 chunks. 8 waves (2Mx4N), wave tile 64x64, acc[4][4] 16x16x32.
// wt gll-staged double-buffered; ft packed from x regs prefetched ONE CHUNK AHEAD (issue-early,
// consume-late) so pack-VALU never waits mid-iteration and the barrier vmcnt drain is covered.
__global__ __launch_bounds__(512,4) void k_gemm(const float* __restrict__ x,
                                                const float* __restrict__ ws,
                                                const u16* __restrict__ wrT,
                                                const u16* __restrict__ amin,
                                                u16* __restrict__ parts){
  __shared__ u16 wt[2][8192];      // 32 KB  [o][32] swizzled
  __shared__ u16 ft[2][4096];      // 16 KB  [m][32] swizzled
  __shared__ float pscale[512];
  __shared__ float pshsub[512];

  int t = threadIdx.x;
  int d = blockIdx.x;
  int mtile = d & 63, s = d >> 6;
  int brow = mtile * 128;
  bool isMin = (s >= 6);

  if (!isMin){
    pscale[t] = ws[WS_SCALE + t];
    pshsub[t] = ws[WS_SHSUB + s*512 + t];
  }

  int row = t >> 2, g = t & 3;
  int ftw = row*32 + ((g ^ ((row >> 1) & 3))*8);
  int wuni = t & ~63;
  const float* xrow = x + (size_t)(brow + row)*512;
  const u16* aminrow = amin + (size_t)(brow + row)*1024 + (isMin ? (s-6)*512 : 0) + g*8;
  const u16* wbase = wrT + (size_t)(s*16)*8192;

  int lane = t & 63, wv = t >> 6;
  int wm = wv >> 2, wn = wv & 3;
  int lr = lane & 15, lk = lane >> 4;
  int g16 = (lk ^ ((lr >> 1) & 3)) * 8;
  f32x4 acc[4][4] = {};
  float4 xa[2][2];                 // x prefetch, double-buffered

  auto loadX = [&](int cc, int xb){
    int col = cc*32 + g*8;
    xa[xb][0] = *(const float4*)(xrow + col);
    xa[xb][1] = *(const float4*)(xrow + col + 4);
  };
  auto stageW = [&](int cc, int nb){
    const u16* wsrc = wbase + (size_t)cc*8192;
    gll16(&wt[nb][wuni*8], wsrc + (size_t)t*8);
    gll16(&wt[nb][4096 + wuni*8], wsrc + 4096 + (size_t)t*8);
    if (isMin) gll16(&ft[nb][wuni*8], aminrow + cc*32);
  };
  auto packFT = [&](int cc, int nb, int xb){
    int col = cc*32 + g*8;
    float4 a0 = xa[xb][0], a1 = xa[xb][1];
    float4 sc0 = *(const float4*)(pscale + col);
    float4 sc1 = *(const float4*)(pscale + col + 4);
    float4 h0  = *(const float4*)(pshsub + col);
    float4 h1  = *(const float4*)(pshsub + col + 4);
    union { bf16x8 v; uint32 u[4]; } R;
    R.u[0] = pk2(fmaxf(fmaf(a0.x,sc0.x,h0.x),0.f), fmaxf(fmaf(a0.y,sc0.y,h0.y),0.f));
    R.u[1] = pk2(fmaxf(fmaf(a0.z,sc0.z,h0.z),0.f), fmaxf(fmaf(a0.w,sc0.w,h0.w),0.f));
    R.u[2] = pk2(fmaxf(fmaf(a1.x,sc1.x,h1.x),0.f), fmaxf(fmaf(a1.y,sc1.y,h1.y),0.f));
    R.u[3] = pk2(fmaxf(fmaf(a1.z,sc1.z,h1.z),0.f), fmaxf(fmaf(a1.w,sc1.w,h1.w),0.f));
    *(bf16x8*)(&ft[nb][ftw]) = R.v;
  };
  auto compute = [&](int cb){
    bf16x8 A[4], Bv[4];
    #pragma unroll
    for (int mi=0; mi<4; ++mi)
      A[mi] = *(const bf16x8*)(&ft[cb][(wm*64 + mi*16 + lr)*32 + g16]);
    #pragma unroll
    for (int ni=0; ni<4; ++ni)
      Bv[ni] = *(const bf16x8*)(&wt[cb][(wn*64 + ni*16 + lr)*32 + g16]);
    #pragma unroll
    for (int mi=0; mi<4; ++mi)
      #pragma unroll
      for (int ni=0; ni<4; ++ni)
        acc[mi][ni] = __builtin_amdgcn_mfma_f32_16x16x32_bf16(A[mi], Bv[ni], acc[mi][ni], 0, 0, 0);
  };

  __syncthreads();   // params visible
  if (!isMin) loadX(0, 0);
  stageW(0, 0);
  if (!isMin){ packFT(0, 0, 0); loadX(1, 1); }
  __syncthreads();

  int cur = 0;
  for (int c=0; c<16; ++c){
    if (!isMin && c < 14) loadX(c+2, c & 1);        // issue earliest: lands by next iter's pack
    if (c < 15){
      stageW(c+1, cur^1);
      if (!isMin) packFT(c+1, cur^1, (c+1) & 1);    // consumes regs loaded last iter: no wait
    }
    compute(cur);
    __syncthreads();
    cur ^= 1;
  }

  u16* pp = parts + ((size_t)s*8192 + brow)*256;
  #pragma unroll
  for (int mi=0; mi<4; ++mi)
    #pragma unroll
    for (int ni=0; ni<4; ++ni)
      #pragma unroll
      for (int r=0; r<4; ++r){
        int rl = wm*64 + mi*16 + lk*4 + r;
        int cl = wn*64 + ni*16 + lr;
        pp[(size_t)rl*256 + cl] = f2bf(acc[mi][ni][r]);
      }
}

// ---------------- reduce 8 bf16 partials + bias ----------------
__global__ __launch_bounds__(256) void k_reduce(const u16* __restrict__ parts,
                                                const float* __restrict__ biases,
                                                float* __restrict__ out){
  int i = (blockIdx.x*256 + threadIdx.x) * 8;
  float b = biases[0];
  float a[8];
  #pragma unroll
  for (int j=0;j<8;++j) a[j] = b;
  #pragma unroll
  for (int s2=0;s2<8;++s2){
    bf16x8 v = *(const bf16x8*)(parts + (size_t)s2*2097152 + i);
    #pragma unroll
    for (int j=0;j<8;++j) a[j] += bf2f((u16)v[j]);
  }
  float4 o0 = {a[0],a[1],a[2],a[3]}, o1 = {a[4],a[5],a[6],a[7]};
  *(float4*)(out + i) = o0;
  *(float4*)(out + i + 4) = o1;
}

extern "C" void kernel_launch(void* const* d_in, const int* in_sizes, int n_in,
                              void* d_out, int out_size, void* d_ws, size_t ws_size,
                              hipStream_t stream){
  const float* x      = (const float*)d_in[0];
  const float* beta   = (const float*)d_in[1];
  const float* gamma  = (const float*)d_in[2];
  const float* w      = (const float*)d_in[3];
  const float* biases = (const float*)d_in[4];
  const int*   ci     = (const int*)d_in[5];
  float* out = (float*)d_out;
  float* wsf = (float*)d_ws;
  u16* wrT   = (u16*)((char*)d_ws + WRT_OFF);
  u16* amin  = (u16*)((char*)d_ws + AMIN_OFF);
  u16* parts = (u16*)((char*)d_ws + PART_OFF);

  k_pre         <<<384, 512, 0, stream>>>(x, w, wsf, wrT);
  k_stats_final <<<16,  512, 0, stream>>>(beta, gamma, wsf);
  k_minfeat     <<<1024,256, 0, stream>>>(x, wsf, ci, amin);
  k_gemm        <<<512, 512, 0, stream>>>(x, wsf, wrT, amin, parts);
  k_reduce      <<<1024,256, 0, stream>>>(parts, biases, out);
}